// Round 1
// baseline (3536.337 us; speedup 1.0000x reference)
//
#include <hip/hip_runtime.h>
#include <hip/hip_bf16.h>
#include <math.h>

#define B_  2
#define T_  2048
#define D_  1024
#define H_  16
#define DH_ 64

// ---------------------------------------------------------------------------
// GEMM: C[M,N] = A[M,K] * B[N,K]^T   (both row-major, K contiguous), f32.
// 64x64 tile, BK=32, 256 threads, each thread computes a 4x4 sub-tile.
// ---------------------------------------------------------------------------
__global__ __launch_bounds__(256) void gemm_abt(
    const float* __restrict__ A, const float* __restrict__ Bm,
    float* __restrict__ C, int M, int N, int K)
{
    __shared__ float As[64][36];   // +4 pad: float4-aligned rows, bank shift 4
    __shared__ float Bs[64][36];
    const int bm  = blockIdx.y << 6;
    const int bn  = blockIdx.x << 6;
    const int tid = threadIdx.x;
    const int rg  = tid >> 4;      // 0..15 row group
    const int cg  = tid & 15;      // 0..15 col group
    float acc[4][4] = {};

    for (int k0 = 0; k0 < K; k0 += 32) {
#pragma unroll
        for (int e = 0; e < 8; ++e) {
            int ii = (e << 8) + tid;
            int r  = ii >> 5, kk = ii & 31;
            As[r][kk] = A[(size_t)(bm + r) * K + k0 + kk];
            Bs[r][kk] = Bm[(size_t)(bn + r) * K + k0 + kk];
        }
        __syncthreads();
#pragma unroll
        for (int k4 = 0; k4 < 8; ++k4) {
            float4 a4[4], b4[4];
#pragma unroll
            for (int i = 0; i < 4; ++i)
                a4[i] = *reinterpret_cast<const float4*>(&As[4*rg + i][k4*4]);
#pragma unroll
            for (int j = 0; j < 4; ++j)
                b4[j] = *reinterpret_cast<const float4*>(&Bs[4*cg + j][k4*4]);
#pragma unroll
            for (int i = 0; i < 4; ++i)
#pragma unroll
                for (int j = 0; j < 4; ++j) {
                    acc[i][j] += a4[i].x * b4[j].x;
                    acc[i][j] += a4[i].y * b4[j].y;
                    acc[i][j] += a4[i].z * b4[j].z;
                    acc[i][j] += a4[i].w * b4[j].w;
                }
        }
        __syncthreads();
    }
#pragma unroll
    for (int i = 0; i < 4; ++i)
#pragma unroll
        for (int j = 0; j < 4; ++j)
            C[(size_t)(bm + 4*rg + i) * N + bn + 4*cg + j] = acc[i][j];
}

// ---------------------------------------------------------------------------
// RoPE in-place on [B,T,H,dh] f32 (theta=10000).  One thread per (re,im) pair.
// pair p: i = p%32 (freq idx), t = (p/512)%T.
// ---------------------------------------------------------------------------
__global__ __launch_bounds__(256) void rope_inplace(float* __restrict__ X)
{
    const int p = blockIdx.x * 256 + threadIdx.x;  // 0 .. 2^21-1 (exact grid)
    const int i = p & 31;
    const int t = (p >> 9) & (T_ - 1);
    const float freq = __powf(10000.f, -(float)i * (1.f / 32.f));
    float sn, cs;
    sincosf((float)t * freq, &sn, &cs);
    float2 v = *reinterpret_cast<const float2*>(&X[2 * p]);
    float2 r;
    r.x = v.x * cs - v.y * sn;
    r.y = v.x * sn + v.y * cs;
    *reinterpret_cast<float2*>(&X[2 * p]) = r;
}

// ---------------------------------------------------------------------------
// Flash-style causal attention.  Q,K,V,O layout: [B, T, H, dh] f32.
// Block = (q-tile of 64 rows) x (b,h).  256 threads; each owns a 4x4 patch.
// Online softmax: per-row m,l held redundantly across the 16 col-group lanes,
// reduced with __shfl_xor (the 16 lanes are contiguous within a wave).
// ---------------------------------------------------------------------------
__global__ __launch_bounds__(256) void attn_fwd(
    const float* __restrict__ Qf, const float* __restrict__ Kf,
    const float* __restrict__ Vf, float* __restrict__ Of)
{
    __shared__ float          Qs[64][68];
    __shared__ float          Ks[64][68];
    __shared__ float          Ss[64][68];
    __shared__ __hip_bfloat16 Vs[64][68];

    const int qt = blockIdx.x;         // q tile 0..31
    const int bh = blockIdx.y;         // 0..31
    const int b  = bh >> 4, h = bh & 15;
    const int q0 = qt << 6;
    const int tid = threadIdx.x;
    const int rg  = tid >> 4, cg = tid & 15;

    // stage Q tile
#pragma unroll
    for (int e = 0; e < 16; ++e) {
        int ii = (e << 8) + tid;
        int r = ii >> 6, d = ii & 63;
        Qs[r][d] = Qf[(size_t)(b * T_ + q0 + r) * D_ + h * DH_ + d];
    }

    float m_i[4], l_i[4], o[4][4] = {};
#pragma unroll
    for (int i = 0; i < 4; ++i) { m_i[i] = -INFINITY; l_i[i] = 0.f; }

    for (int kt = 0; kt <= qt; ++kt) {
        const int k0 = kt << 6;
        __syncthreads();               // prev iter done reading Ks/Vs (and Q visible)
#pragma unroll
        for (int e = 0; e < 16; ++e) {
            int ii = (e << 8) + tid;
            int r = ii >> 6, d = ii & 63;
            size_t g = (size_t)(b * T_ + k0 + r) * D_ + h * DH_ + d;
            Ks[r][d] = Kf[g];
            Vs[r][d] = __float2bfloat16(Vf[g]);
        }
        __syncthreads();

        // S = (Q K^T) * 1/8, causal-masked
        float s[4][4] = {};
#pragma unroll
        for (int k4 = 0; k4 < 16; ++k4) {
            float4 a4[4], b4[4];
#pragma unroll
            for (int i = 0; i < 4; ++i)
                a4[i] = *reinterpret_cast<const float4*>(&Qs[4*rg + i][k4*4]);
#pragma unroll
            for (int j = 0; j < 4; ++j)
                b4[j] = *reinterpret_cast<const float4*>(&Ks[4*cg + j][k4*4]);
#pragma unroll
            for (int i = 0; i < 4; ++i)
#pragma unroll
                for (int j = 0; j < 4; ++j) {
                    s[i][j] += a4[i].x * b4[j].x;
                    s[i][j] += a4[i].y * b4[j].y;
                    s[i][j] += a4[i].z * b4[j].z;
                    s[i][j] += a4[i].w * b4[j].w;
                }
        }

        // online softmax update (per owned row)
#pragma unroll
        for (int i = 0; i < 4; ++i) {
            const int qi = q0 + 4*rg + i;
            float sv[4];
#pragma unroll
            for (int j = 0; j < 4; ++j) {
                const int ki = k0 + 4*cg + j;
                sv[j] = (ki <= qi) ? s[i][j] * 0.125f : -INFINITY;
            }
            float mv = fmaxf(fmaxf(sv[0], sv[1]), fmaxf(sv[2], sv[3]));
#pragma unroll
            for (int off = 1; off < 16; off <<= 1)
                mv = fmaxf(mv, __shfl_xor(mv, off, 64));
            const float mnew = fmaxf(m_i[i], mv);
            const float corr = __expf(m_i[i] - mnew);   // 0 on first tile
            float ps = 0.f;
#pragma unroll
            for (int j = 0; j < 4; ++j) {
                float p = __expf(sv[j] - mnew);
                ps += p;
                Ss[4*rg + i][4*cg + j] = p;
            }
#pragma unroll
            for (int off = 1; off < 16; off <<= 1)
                ps += __shfl_xor(ps, off, 64);
            l_i[i] = l_i[i] * corr + ps;
            m_i[i] = mnew;
#pragma unroll
            for (int j = 0; j < 4; ++j) o[i][j] *= corr;
        }
        __syncthreads();               // P fully in LDS

        // O += P * V
#pragma unroll
        for (int k4 = 0; k4 < 16; ++k4) {
            float pv[4][4], vv[4][4];
#pragma unroll
            for (int i = 0; i < 4; ++i) {
                float4 t = *reinterpret_cast<const float4*>(&Ss[4*rg + i][k4*4]);
                pv[i][0] = t.x; pv[i][1] = t.y; pv[i][2] = t.z; pv[i][3] = t.w;
            }
#pragma unroll
            for (int kk = 0; kk < 4; ++kk) {
                const __hip_bfloat16* vp = &Vs[k4*4 + kk][4*cg];
#pragma unroll
                for (int j = 0; j < 4; ++j) vv[kk][j] = __bfloat162float(vp[j]);
            }
#pragma unroll
            for (int i = 0; i < 4; ++i)
#pragma unroll
                for (int j = 0; j < 4; ++j)
#pragma unroll
                    for (int kk = 0; kk < 4; ++kk)
                        o[i][j] += pv[i][kk] * vv[kk][j];
        }
    }

    // epilogue: normalize and store (layout [B,T,H,dh] => directly the
    // [4096,1024] A-matrix of the output projection)
#pragma unroll
    for (int i = 0; i < 4; ++i) {
        const float inv = 1.f / l_i[i];
#pragma unroll
        for (int j = 0; j < 4; ++j)
            Of[(size_t)(b * T_ + q0 + 4*rg + i) * D_ + h * DH_ + 4*cg + j] =
                o[i][j] * inv;
    }
}

// ---------------------------------------------------------------------------
extern "C" void kernel_launch(void* const* d_in, const int* in_sizes, int n_in,
                              void* d_out, int out_size, void* d_ws, size_t ws_size,
                              hipStream_t stream)
{
    const float* x  = (const float*)d_in[0];
    const float* wq = (const float*)d_in[1];
    const float* wk = (const float*)d_in[2];
    const float* wv = (const float*)d_in[3];
    const float* wo = (const float*)d_in[4];
    float* out = (float*)d_out;

    const size_t NELT = (size_t)B_ * T_ * D_;   // 4,194,304 floats
    float* Qf = (float*)d_ws;
    float* Kf = Qf + NELT;
    float* Vf = Kf + NELT;
    float* Of = Vf + NELT;

    const dim3 gg(D_ / 64, (B_ * T_) / 64);     // (16, 64)

    gemm_abt<<<gg, 256, 0, stream>>>(x, wq, Qf, B_ * T_, D_, D_);
    gemm_abt<<<gg, 256, 0, stream>>>(x, wk, Kf, B_ * T_, D_, D_);
    gemm_abt<<<gg, 256, 0, stream>>>(x, wv, Vf, B_ * T_, D_, D_);

    const int npair_blocks = (B_ * T_ * H_ * (DH_ / 2)) / 256;  // 8192
    rope_inplace<<<npair_blocks, 256, 0, stream>>>(Qf);
    rope_inplace<<<npair_blocks, 256, 0, stream>>>(Kf);

    attn_fwd<<<dim3(T_ / 64, B_ * H_), 256, 0, stream>>>(Qf, Kf, Vf, Of);

    gemm_abt<<<gg, 256, 0, stream>>>(Of, wo, out, B_ * T_, D_, D_);
}

// Round 2
// 318.065 us; speedup vs baseline: 11.1183x; 11.1183x over previous
//
#include <hip/hip_runtime.h>
#include <hip/hip_bf16.h>
#include <math.h>

#define B_  2
#define T_  2048
#define D_  1024
#define H_  16
#define DH_ 64
#define TOK (B_*T_)   // 4096

typedef __attribute__((ext_vector_type(8))) short bf16x8;
typedef __attribute__((ext_vector_type(4))) float f32x4;

static __device__ __forceinline__ float bf2f(short u) {
    union { unsigned int i; float f; } c;
    c.i = ((unsigned int)(unsigned short)u) << 16;
    return c.f;
}
static __device__ __forceinline__ short f2bf(float f) {
    union { float f; unsigned int i; } c; c.f = f;
    unsigned int r = c.i + 0x7fff + ((c.i >> 16) & 1);   // RTNE
    return (short)(r >> 16);
}

// ---------------------------------------------------------------------------
// f32 -> bf16 cast, 8 elements / thread
// ---------------------------------------------------------------------------
__global__ __launch_bounds__(256) void cast_bf16(const float* __restrict__ in,
                                                 short* __restrict__ out, int n8)
{
    int i = blockIdx.x * 256 + threadIdx.x;
    if (i < n8) {
        const float4* p = reinterpret_cast<const float4*>(in);
        float4 a = p[2*i], b = p[2*i+1];
        bf16x8 o;
        o[0] = f2bf(a.x); o[1] = f2bf(a.y); o[2] = f2bf(a.z); o[3] = f2bf(a.w);
        o[4] = f2bf(b.x); o[5] = f2bf(b.y); o[6] = f2bf(b.z); o[7] = f2bf(b.w);
        reinterpret_cast<bf16x8*>(out)[i] = o;
    }
}

// ---------------------------------------------------------------------------
// RoPE cos/sin table: tab[t*32+i] = {cos, sin} of t * 10000^(-i/32)
// ---------------------------------------------------------------------------
__global__ __launch_bounds__(256) void rope_table(float2* __restrict__ tab)
{
    int idx = blockIdx.x * 256 + threadIdx.x;   // T_*32 = 65536
    int t = idx >> 5, i = idx & 31;
    float freq = __powf(10000.f, -(float)i * (1.0f / 32.0f));
    float s, c;
    sincosf((float)t * freq, &s, &c);
    tab[idx] = make_float2(c, s);
}

// ---------------------------------------------------------------------------
// RoPE apply in-place on bf16 [TOK, D].  4 (re,im) pairs = 16B per thread.
// ---------------------------------------------------------------------------
__global__ __launch_bounds__(256) void rope_apply(short* __restrict__ X,
                                                  const float2* __restrict__ tab)
{
    int q = blockIdx.x * 256 + threadIdx.x;     // quad id, total 512K
    int p0 = q << 2;                            // first pair id
    int tt = (p0 >> 9) & (T_ - 1);
    int i0 = p0 & 31;
    int4 v = reinterpret_cast<int4*>(X)[q];
    int out[4]; int vv[4] = {v.x, v.y, v.z, v.w};
#pragma unroll
    for (int j = 0; j < 4; ++j) {
        float2 cs = tab[tt * 32 + i0 + j];
        float re = bf2f((short)(vv[j] & 0xffff));
        float im = bf2f((short)(((unsigned int)vv[j]) >> 16));
        float nr = re * cs.x - im * cs.y;
        float ni = re * cs.y + im * cs.x;
        out[j] = (int)(unsigned short)f2bf(nr) |
                 ((int)(unsigned short)f2bf(ni) << 16);
    }
    reinterpret_cast<int4*>(X)[q] = make_int4(out[0], out[1], out[2], out[3]);
}

// ---------------------------------------------------------------------------
// bf16 MFMA GEMM: C[M,1024-chunk] = A[M,K] * Bsel[1024,K]^T  (m97 structure)
// 128x128 tile, BK=32, 4 waves (2x2, each 64x64 = 4x4 frags of 16x16x32).
// blockIdx.x: 8 col-blocks per output, sel = x>>3 picks (B,out) pair.
// ---------------------------------------------------------------------------
template<int BF16OUT>
__global__ __launch_bounds__(256) void gemm_abt_mfma(
    const short* __restrict__ A,
    const short* __restrict__ B0, const short* __restrict__ B1, const short* __restrict__ B2,
    short* __restrict__ Ob0, short* __restrict__ Ob1, short* __restrict__ Ob2,
    float* __restrict__ Of0, int K)
{
    __shared__ short As[128 * 32];   // linear (global_load_lds requirement)
    __shared__ short Bs[128 * 32];
    const int sel = blockIdx.x >> 3;
    const int bn  = (blockIdx.x & 7) << 7;
    const int bm  = blockIdx.y << 7;
    const short* Bm = sel == 0 ? B0 : (sel == 1 ? B1 : B2);
    short* Obp      = sel == 0 ? Ob0 : (sel == 1 ? Ob1 : Ob2);
    const int tid  = threadIdx.x;
    const int wv   = tid >> 6, lane = tid & 63;
    const int wr   = wv >> 1,  wc   = wv & 1;
    const int fr   = lane & 15, fg  = lane >> 4;
    const int srow  = lane >> 2;          // 0..15 row within 16-row chunk
    const int skoff = (lane & 3) << 3;    // k offset 0/8/16/24
    f32x4 acc[4][4] = {};

    for (int k0 = 0; k0 < K; k0 += 32) {
        __syncthreads();
#pragma unroll
        for (int it = 0; it < 2; ++it) {
            const int c = wv * 2 + it;            // wave-uniform chunk 0..7
            const int r = 16 * c + srow;
            __builtin_amdgcn_global_load_lds(
                (const __attribute__((address_space(1))) unsigned int*)
                    (A + (size_t)(bm + r) * K + k0 + skoff),
                (__attribute__((address_space(3))) unsigned int*)(As + c * 512),
                16, 0, 0);
            __builtin_amdgcn_global_load_lds(
                (const __attribute__((address_space(1))) unsigned int*)
                    (Bm + (size_t)(bn + r) * K + k0 + skoff),
                (__attribute__((address_space(3))) unsigned int*)(Bs + c * 512),
                16, 0, 0);
        }
        __syncthreads();
        bf16x8 af[4], bfr[4];
#pragma unroll
        for (int m = 0; m < 4; ++m)
            af[m] = *(const bf16x8*)(As + (wr * 64 + m * 16 + fr) * 32 + fg * 8);
#pragma unroll
        for (int n = 0; n < 4; ++n)
            bfr[n] = *(const bf16x8*)(Bs + (wc * 64 + n * 16 + fr) * 32 + fg * 8);
#pragma unroll
        for (int m = 0; m < 4; ++m)
#pragma unroll
            for (int n = 0; n < 4; ++n)
                acc[m][n] = __builtin_amdgcn_mfma_f32_16x16x32_bf16(
                                af[m], bfr[n], acc[m][n], 0, 0, 0);
    }
    // epilogue: C/D layout col=lane&15, row=(lane>>4)*4+j  [m89]
    const int row0 = bm + wr * 64 + fg * 4;
    const int col0 = bn + wc * 64 + fr;
#pragma unroll
    for (int m = 0; m < 4; ++m)
#pragma unroll
        for (int n = 0; n < 4; ++n)
#pragma unroll
            for (int j = 0; j < 4; ++j) {
                const size_t idx = (size_t)(row0 + m * 16 + j) * 1024 + col0 + n * 16;
                if (BF16OUT) Obp[idx] = f2bf(acc[m][n][j]);
                else         Of0[idx] = acc[m][n][j];
            }
}

// ---------------------------------------------------------------------------
// Flash attention, bf16 MFMA.  Block = 64 q-rows x (b,h); 4 waves, each owns
// 16 q-rows.  K tile and transposed-V tile in XOR-swizzled LDS (G4); P goes
// through swizzled LDS for the C-layout -> A-layout lane redistribution.
// ---------------------------------------------------------------------------
__global__ __launch_bounds__(256) void attn_mfma(
    const short* __restrict__ Qb, const short* __restrict__ Kb,
    const short* __restrict__ Vb, short* __restrict__ Ob)
{
    __shared__ short Ks[64 * 64];   // [k][d], row 128B, swizzled
    __shared__ short Vt[64 * 64];   // [d][k], row 128B, swizzled (transposed V)
    __shared__ short Ps[64 * 64];   // [q][k], row 128B, swizzled

    const int qt = (int)(gridDim.x - 1) - (int)blockIdx.x;   // heavy tiles first
    const int bh = blockIdx.y;
    const int b  = bh >> 4, h = bh & 15;
    const int q0 = qt << 6;
    const int tid  = threadIdx.x;
    const int wv   = tid >> 6, lane = tid & 63;
    const int fr   = lane & 15, fg = lane >> 4;

    // Q A-fragments (held in registers): row = q0 + 16*wv + fr
    const size_t qrow = (size_t)(b * T_ + q0 + wv * 16 + fr);
    const short* qp = Qb + qrow * D_ + h * DH_;
    const bf16x8 qf0 = *(const bf16x8*)(qp + fg * 8);
    const bf16x8 qf1 = *(const bf16x8*)(qp + 32 + fg * 8);

    float m_i[4], l_i[4];
    f32x4 oa[4] = {};
#pragma unroll
    for (int j = 0; j < 4; ++j) { m_i[j] = -1e30f; l_i[j] = 0.f; }

    // staging assignment: thread covers 16B chunks (row sr, d-off sdoff)
    const int sdoff = (tid & 7) << 3;
    const int sr0   = tid >> 3;           // 0..31
    const int sr1   = sr0 + 32;
    const short* kbase = Kb + (size_t)b * T_ * D_ + h * DH_ + sdoff;
    const short* vbase = Vb + (size_t)b * T_ * D_ + h * DH_ + sdoff;

    for (int kt = 0; kt <= qt; ++kt) {
        const int k0 = kt << 6;
        const bf16x8 kr0 = *(const bf16x8*)(kbase + (size_t)(k0 + sr0) * D_);
        const bf16x8 kr1 = *(const bf16x8*)(kbase + (size_t)(k0 + sr1) * D_);
        const bf16x8 vr0 = *(const bf16x8*)(vbase + (size_t)(k0 + sr0) * D_);
        const bf16x8 vr1 = *(const bf16x8*)(vbase + (size_t)(k0 + sr1) * D_);
        __syncthreads();                       // prior tile's LDS reads done
        *(bf16x8*)(Ks + ((sr0 * 64 + sdoff) ^ ((sr0 & 7) << 3))) = kr0;
        *(bf16x8*)(Ks + ((sr1 * 64 + sdoff) ^ ((sr1 & 7) << 3))) = kr1;
#pragma unroll
        for (int jj = 0; jj < 8; ++jj) {       // V transpose, rotated order
            const int j0 = (jj + (tid & 7)) & 7;
            const int d0 = sdoff + j0;
            Vt[(d0 * 64 + sr0) ^ ((d0 & 7) << 3)] = vr0[j0];
            Vt[(d0 * 64 + sr1) ^ ((d0 & 7) << 3)] = vr1[j0];
        }
        __syncthreads();                       // staging visible

        // S = Q K^T   (4 k-col frags x 2 d-chunks)
        f32x4 sc[4] = {};
#pragma unroll
        for (int f = 0; f < 4; ++f) {
            const int krow = 16 * f + fr;
            const bf16x8 b0 = *(const bf16x8*)(Ks + ((krow * 64 + fg * 8)      ^ ((krow & 7) << 3)));
            const bf16x8 b1 = *(const bf16x8*)(Ks + ((krow * 64 + 32 + fg * 8) ^ ((krow & 7) << 3)));
            sc[f] = __builtin_amdgcn_mfma_f32_16x16x32_bf16(qf0, b0, sc[f], 0, 0, 0);
            sc[f] = __builtin_amdgcn_mfma_f32_16x16x32_bf16(qf1, b1, sc[f], 0, 0, 0);
        }

        // online softmax (wave-parallel, 16-lane group reductions)
#pragma unroll
        for (int j = 0; j < 4; ++j) {
            const int qg = q0 + 16 * wv + 4 * fg + j;
            float pv[4];
#pragma unroll
            for (int f = 0; f < 4; ++f) {
                const int kg = k0 + 16 * f + fr;
                const float x = sc[f][j] * 0.125f;
                pv[f] = (kg <= qg) ? x : -1e30f;
            }
            float mv = fmaxf(fmaxf(pv[0], pv[1]), fmaxf(pv[2], pv[3]));
            mv = fmaxf(mv, __shfl_xor(mv, 1));
            mv = fmaxf(mv, __shfl_xor(mv, 2));
            mv = fmaxf(mv, __shfl_xor(mv, 4));
            mv = fmaxf(mv, __shfl_xor(mv, 8));
            const float mnew = fmaxf(m_i[j], mv);
            const float corr = __expf(m_i[j] - mnew);
            m_i[j] = mnew;
            float ps = 0.f;
            const int qa = 16 * wv + 4 * fg + j;
#pragma unroll
            for (int f = 0; f < 4; ++f) {
                const float e = __expf(pv[f] - mnew);
                ps += e;
                Ps[(qa * 64 + 16 * f + fr) ^ ((qa & 7) << 3)] = f2bf(e);
            }
            ps += __shfl_xor(ps, 1); ps += __shfl_xor(ps, 2);
            ps += __shfl_xor(ps, 4); ps += __shfl_xor(ps, 8);
            l_i[j] = l_i[j] * corr + ps;
#pragma unroll
            for (int n = 0; n < 4; ++n) oa[n][j] *= corr;
        }

        // O += P V   (own-wave P rows only -> no barrier needed)
#pragma unroll
        for (int kc = 0; kc < 2; ++kc) {
            const int qa = 16 * wv + fr;
            const bf16x8 pa = *(const bf16x8*)(Ps + ((qa * 64 + kc * 32 + fg * 8) ^ ((qa & 7) << 3)));
#pragma unroll
            for (int n = 0; n < 4; ++n) {
                const int dr = 16 * n + fr;
                const bf16x8 vb = *(const bf16x8*)(Vt + ((dr * 64 + kc * 32 + fg * 8) ^ ((dr & 7) << 3)));
                oa[n] = __builtin_amdgcn_mfma_f32_16x16x32_bf16(pa, vb, oa[n], 0, 0, 0);
            }
        }
    }

    // epilogue: O /= l, write bf16 [b, t, h*64+d]
#pragma unroll
    for (int j = 0; j < 4; ++j) {
        const float inv = 1.f / l_i[j];
        const size_t orow = (size_t)(b * T_ + q0 + 16 * wv + 4 * fg + j);
#pragma unroll
        for (int n = 0; n < 4; ++n)
            Ob[orow * D_ + h * DH_ + 16 * n + fr] = f2bf(oa[n][j] * inv);
    }
}

// ---------------------------------------------------------------------------
extern "C" void kernel_launch(void* const* d_in, const int* in_sizes, int n_in,
                              void* d_out, int out_size, void* d_ws, size_t ws_size,
                              hipStream_t stream)
{
    const float* x  = (const float*)d_in[0];
    const float* wq = (const float*)d_in[1];
    const float* wk = (const float*)d_in[2];
    const float* wv = (const float*)d_in[3];
    const float* wo = (const float*)d_in[4];
    float* out = (float*)d_out;

    const size_t NTOK = (size_t)TOK * D_;    // 4M elems
    const size_t NW   = (size_t)D_ * D_;     // 1M elems
    short* xb  = (short*)d_ws;
    short* wqb = xb  + NTOK;
    short* wkb = wqb + NW;
    short* wvb = wkb + NW;
    short* wob = wvb + NW;
    short* Qb  = wob + NW;
    short* Kb  = Qb  + NTOK;
    short* Vb  = Kb  + NTOK;
    short* Obf = Vb  + NTOK;
    float2* tab = (float2*)(Obf + NTOK);

    cast_bf16<<<2048, 256, 0, stream>>>(x,  xb,  (int)(NTOK / 8));
    cast_bf16<<<512,  256, 0, stream>>>(wq, wqb, (int)(NW / 8));
    cast_bf16<<<512,  256, 0, stream>>>(wk, wkb, (int)(NW / 8));
    cast_bf16<<<512,  256, 0, stream>>>(wv, wvb, (int)(NW / 8));
    cast_bf16<<<512,  256, 0, stream>>>(wo, wob, (int)(NW / 8));
    rope_table<<<256, 256, 0, stream>>>(tab);

    // merged QKV projection: [4096,1024] x three [1024,1024]^T
    gemm_abt_mfma<1><<<dim3(24, 32), 256, 0, stream>>>(
        xb, wqb, wkb, wvb, Qb, Kb, Vb, nullptr, D_);

    rope_apply<<<2048, 256, 0, stream>>>(Qb, tab);
    rope_apply<<<2048, 256, 0, stream>>>(Kb, tab);

    attn_mfma<<<dim3(T_ / 64, B_ * H_), 256, 0, stream>>>(Qb, Kb, Vb, Obf);

    // output projection -> f32 d_out
    gemm_abt_mfma<0><<<dim3(8, 32), 256, 0, stream>>>(
        Obf, wob, wob, wob, nullptr, nullptr, nullptr, out, D_);
}

// Round 3
// 276.732 us; speedup vs baseline: 12.7789x; 1.1494x over previous
//
#include <hip/hip_runtime.h>
#include <hip/hip_bf16.h>
#include <math.h>

#define B_  2
#define T_  2048
#define D_  1024
#define H_  16
#define DH_ 64
#define TOK (B_*T_)   // 4096

typedef __attribute__((ext_vector_type(8)))  short bf16x8;
typedef __attribute__((ext_vector_type(4)))  float f32x4;
typedef __attribute__((ext_vector_type(16))) float f32x16;

static __device__ __forceinline__ float bf2f(short u) {
    union { unsigned int i; float f; } c;
    c.i = ((unsigned int)(unsigned short)u) << 16;
    return c.f;
}
static __device__ __forceinline__ short f2bf(float f) {
    union { float f; unsigned int i; } c; c.f = f;
    unsigned int r = c.i + 0x7fff + ((c.i >> 16) & 1);   // RTNE
    return (short)(r >> 16);
}
// v_cvt_pk_bf16_f32: packs {lo, hi} into one u32 (no builtin on gfx950, m240)
static __device__ __forceinline__ unsigned cvtpk(float lo, float hi2) {
    unsigned r;
    asm("v_cvt_pk_bf16_f32 %0, %1, %2" : "=v"(r) : "v"(lo), "v"(hi2));
    return r;
}

// ---------------------------------------------------------------------------
// fused f32 -> bf16 cast for x + 4 weights (one launch)
// chunk = 8 elems; x: 512K chunks, each weight: 128K chunks; grid exact 4096.
// ---------------------------------------------------------------------------
__global__ __launch_bounds__(256) void cast_all(
    const float* __restrict__ x,  const float* __restrict__ wq,
    const float* __restrict__ wk, const float* __restrict__ wv,
    const float* __restrict__ wo,
    short* __restrict__ xb,  short* __restrict__ wqb,
    short* __restrict__ wkb, short* __restrict__ wvb,
    short* __restrict__ wob)
{
    int i = blockIdx.x * 256 + threadIdx.x;       // 0 .. 1048575
    const float* src; short* dst; int off;
    if (i < 524288) { src = x; dst = xb; off = i; }
    else {
        int j = i - 524288;
        int wsel = j >> 17;  off = j & 131071;
        src = wsel == 0 ? wq : wsel == 1 ? wk : wsel == 2 ? wv : wo;
        dst = wsel == 0 ? wqb : wsel == 1 ? wkb : wsel == 2 ? wvb : wob;
    }
    const float4* p = reinterpret_cast<const float4*>(src);
    float4 a = p[2*off], b = p[2*off+1];
    bf16x8 o;
    o[0] = f2bf(a.x); o[1] = f2bf(a.y); o[2] = f2bf(a.z); o[3] = f2bf(a.w);
    o[4] = f2bf(b.x); o[5] = f2bf(b.y); o[6] = f2bf(b.z); o[7] = f2bf(b.w);
    reinterpret_cast<bf16x8*>(dst)[off] = o;
}

// ---------------------------------------------------------------------------
// RoPE cos/sin table: tab[t*32+i] = {cos, sin} of t * 10000^(-i/32)
// ---------------------------------------------------------------------------
__global__ __launch_bounds__(256) void rope_table(float2* __restrict__ tab)
{
    int idx = blockIdx.x * 256 + threadIdx.x;   // T_*32 = 65536
    int t = idx >> 5, i = idx & 31;
    float freq = __powf(10000.f, -(float)i * (1.0f / 32.0f));
    float s, c;
    sincosf((float)t * freq, &s, &c);
    tab[idx] = make_float2(c, s);
}

// ---------------------------------------------------------------------------
// Fused RoPE for Q and K.  Q additionally pre-scaled by 0.125*log2(e) so the
// attention softmax can run in the exp2 domain with zero per-element scaling.
// ---------------------------------------------------------------------------
__global__ __launch_bounds__(256) void rope_apply2(short* __restrict__ Q,
                                                   short* __restrict__ K,
                                                   const float2* __restrict__ tab)
{
    int g = blockIdx.x * 256 + threadIdx.x;     // 0 .. 2*512K-1
    short* X;
    float sc;
    int q;
    if (g < 524288) { X = Q; sc = 0.18033688011112042f; q = g; }
    else            { X = K; sc = 1.0f;                 q = g - 524288; }
    int p0 = q << 2;
    int tt = (p0 >> 9) & (T_ - 1);
    int i0 = p0 & 31;
    int4 v = reinterpret_cast<int4*>(X)[q];
    int out[4]; int vv[4] = {v.x, v.y, v.z, v.w};
#pragma unroll
    for (int j = 0; j < 4; ++j) {
        float2 cs = tab[tt * 32 + i0 + j];
        float re = bf2f((short)(vv[j] & 0xffff));
        float im = bf2f((short)(((unsigned int)vv[j]) >> 16));
        float nr = (re * cs.x - im * cs.y) * sc;
        float ni = (re * cs.y + im * cs.x) * sc;
        out[j] = (int)(unsigned short)f2bf(nr) |
                 ((int)(unsigned short)f2bf(ni) << 16);
    }
    reinterpret_cast<int4*>(X)[q] = make_int4(out[0], out[1], out[2], out[3]);
}

// ---------------------------------------------------------------------------
// bf16 MFMA GEMM (m97 structure), unchanged from R2.
// ---------------------------------------------------------------------------
template<int BF16OUT>
__global__ __launch_bounds__(256) void gemm_abt_mfma(
    const short* __restrict__ A,
    const short* __restrict__ B0, const short* __restrict__ B1, const short* __restrict__ B2,
    short* __restrict__ Ob0, short* __restrict__ Ob1, short* __restrict__ Ob2,
    float* __restrict__ Of0, int K)
{
    __shared__ short As[128 * 32];
    __shared__ short Bs[128 * 32];
    const int sel = blockIdx.x >> 3;
    const int bn  = (blockIdx.x & 7) << 7;
    const int bm  = blockIdx.y << 7;
    const short* Bm = sel == 0 ? B0 : (sel == 1 ? B1 : B2);
    short* Obp      = sel == 0 ? Ob0 : (sel == 1 ? Ob1 : Ob2);
    const int tid  = threadIdx.x;
    const int wv   = tid >> 6, lane = tid & 63;
    const int wr   = wv >> 1,  wc   = wv & 1;
    const int fr   = lane & 15, fg  = lane >> 4;
    const int srow  = lane >> 2;
    const int skoff = (lane & 3) << 3;
    f32x4 acc[4][4] = {};

    for (int k0 = 0; k0 < K; k0 += 32) {
        __syncthreads();
#pragma unroll
        for (int it = 0; it < 2; ++it) {
            const int c = wv * 2 + it;
            const int r = 16 * c + srow;
            __builtin_amdgcn_global_load_lds(
                (const __attribute__((address_space(1))) unsigned int*)
                    (A + (size_t)(bm + r) * K + k0 + skoff),
                (__attribute__((address_space(3))) unsigned int*)(As + c * 512),
                16, 0, 0);
            __builtin_amdgcn_global_load_lds(
                (const __attribute__((address_space(1))) unsigned int*)
                    (Bm + (size_t)(bn + r) * K + k0 + skoff),
                (__attribute__((address_space(3))) unsigned int*)(Bs + c * 512),
                16, 0, 0);
        }
        __syncthreads();
        bf16x8 af[4], bfr[4];
#pragma unroll
        for (int m = 0; m < 4; ++m)
            af[m] = *(const bf16x8*)(As + (wr * 64 + m * 16 + fr) * 32 + fg * 8);
#pragma unroll
        for (int n = 0; n < 4; ++n)
            bfr[n] = *(const bf16x8*)(Bs + (wc * 64 + n * 16 + fr) * 32 + fg * 8);
#pragma unroll
        for (int m = 0; m < 4; ++m)
#pragma unroll
            for (int n = 0; n < 4; ++n)
                acc[m][n] = __builtin_amdgcn_mfma_f32_16x16x32_bf16(
                                af[m], bfr[n], acc[m][n], 0, 0, 0);
    }
    const int row0 = bm + wr * 64 + fg * 4;
    const int col0 = bn + wc * 64 + fr;
#pragma unroll
    for (int m = 0; m < 4; ++m)
#pragma unroll
        for (int n = 0; n < 4; ++n)
#pragma unroll
            for (int j = 0; j < 4; ++j) {
                const size_t idx = (size_t)(row0 + m * 16 + j) * 1024 + col0 + n * 16;
                if (BF16OUT) Obp[idx] = f2bf(acc[m][n][j]);
                else         Of0[idx] = acc[m][n][j];
            }
}

// ---------------------------------------------------------------------------
// Flash attention v2: swapped-QK^T 32x32x16 MFMA, in-register softmax.
// Block: 128 q-rows (4 waves x 32), KV tile 64, double-buffered LDS staging.
// Lane (q = lane&31, hi = lane>>5) holds P[q][32 interleaved kv] in regs.
// S^T = mfma(A=K, B=Q)    -> D[kv][q]:  col=lane&31=q (m74 C-layout)
// O^T = mfma(A=V^T, B=P^T)-> D[d][q]:   col=lane&31=q
// Q pre-scaled by 0.125*log2(e) => softmax in exp2 domain.
// ---------------------------------------------------------------------------
__global__ __launch_bounds__(256) void attn_mfma2(
    const short* __restrict__ Qb, const short* __restrict__ Kb,
    const short* __restrict__ Vb, short* __restrict__ Ob)
{
    __shared__ short KsBuf[2][64 * 64];   // [kv][d], XOR-swizzled rows
    __shared__ short VtBuf[2][64 * 64];   // [d][kv], XOR-swizzled rows

    const int qb = (int)(gridDim.x - 1 - blockIdx.x);   // heavy blocks first
    const int bh = blockIdx.y;
    const int b  = bh >> 4, h = bh & 15;
    const int q0 = qb << 7;
    const int tid  = threadIdx.x;
    const int w    = tid >> 6, lane = tid & 63;
    const int ql   = lane & 31, hi = lane >> 5;
    const int qw_lo  = q0 + 32 * w;
    const int q_glob = qw_lo + ql;
    const int nt = (q0 + 128) >> 6;                     // 2qb+2 kv tiles

    // Q fragments (B-operand): lane needs Q[q_glob][16*ds + 8*hi + e]
    const short* qp = Qb + (size_t)(b * T_ + q_glob) * D_ + h * DH_ + hi * 8;
    bf16x8 qf[4];
#pragma unroll
    for (int ds = 0; ds < 4; ++ds)
        qf[ds] = *(const bf16x8*)(qp + 16 * ds);

    float m_run = -3e38f, l_run = 0.f;
    f32x16 accO0, accO1;
#pragma unroll
    for (int r = 0; r < 16; ++r) { accO0[r] = 0.f; accO1[r] = 0.f; }

    // staging map: thread covers rows sr0,sr1 at d-offset sdo (16B chunks)
    const int sr0 = tid >> 3, sr1 = sr0 + 32, sdo = (tid & 7) << 3;
    const short* kbase = Kb + (size_t)b * T_ * D_ + h * DH_ + sdo;
    const short* vbase = Vb + (size_t)b * T_ * D_ + h * DH_ + sdo;

    bf16x8 krA, krB, vrA, vrB;
#define LOADT(t) {                                                        \
        const size_t o_ = (size_t)((t) << 6) * D_;                        \
        krA = *(const bf16x8*)(kbase + o_ + (size_t)sr0 * D_);            \
        krB = *(const bf16x8*)(kbase + o_ + (size_t)sr1 * D_);            \
        vrA = *(const bf16x8*)(vbase + o_ + (size_t)sr0 * D_);            \
        vrB = *(const bf16x8*)(vbase + o_ + (size_t)sr1 * D_); }
#define STORET(bu) {                                                      \
        short* Kp = KsBuf[bu]; short* Vp = VtBuf[bu];                     \
        *(bf16x8*)(Kp + ((sr0 * 64 + sdo) ^ ((sr0 & 7) << 3))) = krA;     \
        *(bf16x8*)(Kp + ((sr1 * 64 + sdo) ^ ((sr1 & 7) << 3))) = krB;     \
        _Pragma("unroll")                                                 \
        for (int jj = 0; jj < 8; ++jj) {                                  \
            const int j0 = (jj + (tid & 7)) & 7;                          \
            const int d0 = sdo + j0;                                      \
            Vp[(d0 * 64 + sr0) ^ ((d0 & 7) << 3)] = vrA[j0];              \
            Vp[(d0 * 64 + sr1) ^ ((d0 & 7) << 3)] = vrB[j0];              \
        } }

    LOADT(0); STORET(0);
    __syncthreads();

    for (int t = 0; t < nt; ++t) {
        const int cur = t & 1;
        const int K0  = t << 6;
        const bool hasNext = (t + 1 < nt);
        if (hasNext) LOADT(t + 1);                       // overlap w/ compute

        if (K0 <= qw_lo + 31) {                          // wave not fully masked
            const short* Kp = KsBuf[cur];
            const short* Vp = VtBuf[cur];
            // ---- S^T = Q K^T (swapped) ----
            f32x16 s0, s1;
#pragma unroll
            for (int r = 0; r < 16; ++r) { s0[r] = 0.f; s1[r] = 0.f; }
#pragma unroll
            for (int ds = 0; ds < 4; ++ds) {
                const int c = 16 * ds + 8 * hi;
                const int r0 = ql, r1 = 32 + ql;
                bf16x8 kf0 = *(const bf16x8*)(Kp + ((r0 * 64 + c) ^ ((r0 & 7) << 3)));
                bf16x8 kf1 = *(const bf16x8*)(Kp + ((r1 * 64 + c) ^ ((r1 & 7) << 3)));
                s0 = __builtin_amdgcn_mfma_f32_32x32x16_bf16(kf0, qf[ds], s0, 0, 0, 0);
                s1 = __builtin_amdgcn_mfma_f32_32x32x16_bf16(kf1, qf[ds], s1, 0, 0, 0);
            }
            // ---- causal mask (diagonal tiles only) ----
            if (K0 + 63 > qw_lo) {
                const int qrel = q_glob - K0;
#pragma unroll
                for (int r = 0; r < 16; ++r) {
                    const int kv0 = 4 * hi + ((r & 3) + 8 * (r >> 2));
                    s0[r] = (kv0      <= qrel) ? s0[r] : -3e38f;
                    s1[r] = (kv0 + 32 <= qrel) ? s1[r] : -3e38f;
                }
            }
            // ---- online softmax, exp2 domain, defer-max (T13) ----
            float mloc = s0[0];
#pragma unroll
            for (int r = 1; r < 16; ++r) mloc = fmaxf(mloc, s0[r]);
#pragma unroll
            for (int r = 0; r < 16; ++r) mloc = fmaxf(mloc, s1[r]);
            mloc = fmaxf(mloc, __shfl_xor(mloc, 32));
            if (!__all(mloc <= m_run + 11.5f)) {
                const float mnew = fmaxf(m_run, mloc);
                const float corr = exp2f(m_run - mnew);
                m_run = mnew;
                l_run *= corr;
#pragma unroll
                for (int r = 0; r < 16; ++r) { accO0[r] *= corr; accO1[r] *= corr; }
            }
            float lsum = 0.f;
#pragma unroll
            for (int r = 0; r < 16; ++r) { s0[r] = exp2f(s0[r] - m_run); lsum += s0[r]; }
#pragma unroll
            for (int r = 0; r < 16; ++r) { s1[r] = exp2f(s1[r] - m_run); lsum += s1[r]; }
            lsum += __shfl_xor(lsum, 32);
            l_run += lsum;
            // ---- pack P to bf16 (T12): W[q4][i] covers kv 32*(q4>>2)+8*(q4&3)+4hi+2i.. ----
            unsigned W[8][2];
#pragma unroll
            for (int q4 = 0; q4 < 4; ++q4) {
                W[q4][0]     = cvtpk(s0[4*q4+0], s0[4*q4+1]);
                W[q4][1]     = cvtpk(s0[4*q4+2], s0[4*q4+3]);
                W[q4 + 4][0] = cvtpk(s1[4*q4+0], s1[4*q4+1]);
                W[q4 + 4][1] = cvtpk(s1[4*q4+2], s1[4*q4+3]);
            }
            // ---- PV: O^T += V^T P^T  (4 kv-slices of 16) ----
#pragma unroll
            for (int sl = 0; sl < 4; ++sl) {
                const int qe = 2 * sl, qo = qe + 1;
                unsigned srcA = hi ? W[qe][0] : W[qo][0];
                unsigned srcB = hi ? W[qe][1] : W[qo][1];
                unsigned xA = (unsigned)__shfl_xor((int)srcA, 32);
                unsigned xB = (unsigned)__shfl_xor((int)srcB, 32);
                union { unsigned u[4]; bf16x8 v; } pu;
                pu.u[0] = hi ? xA : W[qe][0];
                pu.u[1] = hi ? xB : W[qe][1];
                pu.u[2] = hi ? W[qo][0] : xA;
                pu.u[3] = hi ? W[qo][1] : xB;
                const int c = 16 * sl + 8 * hi;
                const int d0 = ql, d1 = 32 + ql;
                bf16x8 vf0 = *(const bf16x8*)(Vp + ((d0 * 64 + c) ^ ((d0 & 7) << 3)));
                bf16x8 vf1 = *(const bf16x8*)(Vp + ((d1 * 64 + c) ^ ((d1 & 7) << 3)));
                accO0 = __builtin_amdgcn_mfma_f32_32x32x16_bf16(vf0, pu.v, accO0, 0, 0, 0);
                accO1 = __builtin_amdgcn_mfma_f32_32x32x16_bf16(vf1, pu.v, accO1, 0, 0, 0);
            }
        }
        if (hasNext) STORET(cur ^ 1);
        __syncthreads();
    }

    // ---- epilogue: O = O^T / l, via LDS transpose, bf16 out ----
    unsigned* Ot = (unsigned*)KsBuf;       // 16 KB, per-wave 4 KB regions
    const float invl = 1.f / l_run;
#pragma unroll
    for (int rq = 0; rq < 4; ++rq) {
        unsigned p0 = cvtpk(accO0[4*rq+0] * invl, accO0[4*rq+1] * invl);
        unsigned p1 = cvtpk(accO0[4*rq+2] * invl, accO0[4*rq+3] * invl);
        unsigned p2 = cvtpk(accO1[4*rq+0] * invl, accO1[4*rq+1] * invl);
        unsigned p3 = cvtpk(accO1[4*rq+2] * invl, accO1[4*rq+3] * invl);
        const int du0 = (4 * hi + 8 * rq) >> 1;
        Ot[w * 1024 + ql * 32 + du0]          = p0;
        Ot[w * 1024 + ql * 32 + du0 + 1]      = p1;
        Ot[w * 1024 + ql * 32 + du0 + 16]     = p2;
        Ot[w * 1024 + ql * 32 + du0 + 16 + 1] = p3;
    }
    __syncthreads();
    {
        const int qq = tid >> 1, half = tid & 1;
        const int4* s4 = (const int4*)(Ot + (qq >> 5) * 1024 + (qq & 31) * 32 + half * 16);
        int4* d4 = (int4*)(Ob + (size_t)(b * T_ + q0 + qq) * D_ + h * DH_ + half * 32);
        d4[0] = s4[0]; d4[1] = s4[1]; d4[2] = s4[2]; d4[3] = s4[3];
    }
#undef LOADT
#undef STORET
}

// ---------------------------------------------------------------------------
extern "C" void kernel_launch(void* const* d_in, const int* in_sizes, int n_in,
                              void* d_out, int out_size, void* d_ws, size_t ws_size,
                              hipStream_t stream)
{
    const float* x  = (const float*)d_in[0];
    const float* wq = (const float*)d_in[1];
    const float* wk = (const float*)d_in[2];
    const float* wv = (const float*)d_in[3];
    const float* wo = (const float*)d_in[4];
    float* out = (float*)d_out;

    const size_t NTOK = (size_t)TOK * D_;
    const size_t NW   = (size_t)D_ * D_;
    short* xb  = (short*)d_ws;
    short* wqb = xb  + NTOK;
    short* wkb = wqb + NW;
    short* wvb = wkb + NW;
    short* wob = wvb + NW;
    short* Qb  = wob + NW;
    short* Kb  = Qb  + NTOK;
    short* Vb  = Kb  + NTOK;
    short* Obf = Vb  + NTOK;
    float2* tab = (float2*)(Obf + NTOK);

    cast_all<<<4096, 256, 0, stream>>>(x, wq, wk, wv, wo,
                                       xb, wqb, wkb, wvb, wob);
    rope_table<<<256, 256, 0, stream>>>(tab);

    gemm_abt_mfma<1><<<dim3(24, 32), 256, 0, stream>>>(
        xb, wqb, wkb, wvb, Qb, Kb, Vb, nullptr, D_);

    rope_apply2<<<4096, 256, 0, stream>>>(Qb, Kb, tab);

    attn_mfma2<<<dim3(T_ / 128, B_ * H_), 256, 0, stream>>>(Qb, Kb, Vb, Obf);

    gemm_abt_mfma<0><<<dim3(8, 32), 256, 0, stream>>>(
        Obf, wob, wob, wob, nullptr, nullptr, nullptr, out, D_);
}